// Round 8
// baseline (215.215 us; speedup 1.0000x reference)
//
#include <hip/hip_runtime.h>
#include <hip/hip_bf16.h>

typedef __bf16 bf16_t;
typedef bf16_t bf16x8 __attribute__((ext_vector_type(8)));
typedef bf16_t bf16x4 __attribute__((ext_vector_type(4)));
typedef float f32x4 __attribute__((ext_vector_type(4)));

#define B_   4
#define S_   1024
#define H_   32
#define KVH_ 8
#define D_   128
#define WIN_ 512
#define KVD_ (KVH_ * D_)                 // 1024
#define LOG2E_ 1.4426950408889634f
// log2-domain softcap: capL = 50*log2e*tanh(score*scale/50)
// Softcap BOUNDS the logits (|capL| <= K2_), so softmax uses a FIXED max:
//   p = exp2(capL - K2_) = exp2(-2*K2_ / (ez+1)),  ez = exp2(score*C1_)
#define C1_ (2.0f * (0.08838834764831845f / 50.0f) * LOG2E_)
#define K2_ (50.0f * LOG2E_)
#define NK22_ (-2.0f * K2_)
#define EXP2F_(x) __builtin_amdgcn_exp2f(x)

__device__ __forceinline__ void async16(const bf16_t* g, bf16_t* l) {
  // global -> LDS DMA, 16B/lane; LDS dest = wave-uniform base + lane*16.
  // Global source is PER-LANE: swizzle lives in the source address (m173).
  __builtin_amdgcn_global_load_lds(
      (const __attribute__((address_space(1))) void*)g,
      (__attribute__((address_space(3))) void*)l, 16, 0, 0);
}

// ---------------- prepass: fp32 K/V -> bf16, head-major; V transposed ------
// (verified rounds 0-2, verbatim)
__global__ __launch_bounds__(256) void prep_kv(
    const float* __restrict__ K, const float* __restrict__ V,
    bf16_t* __restrict__ Kb, bf16_t* __restrict__ Vt)
{
  const int j0  = blockIdx.x * 64;
  const int kvh = blockIdx.y;
  const int b   = blockIdx.z;
  const int t   = threadIdx.x;
  const int j   = t >> 2;                // token row 0..63
  const int d0  = (t & 3) * 32;
  __shared__ bf16_t tl[128][72];

  {
    const float* src = K + (size_t)(b * S_ + j0 + j) * KVD_ + kvh * D_ + d0;
    bf16_t* dst = Kb + ((size_t)(b * KVH_ + kvh) * S_ + j0 + j) * D_ + d0;
    #pragma unroll
    for (int c = 0; c < 4; ++c) {
      float4 f0 = *(const float4*)(src + c * 8);
      float4 f1 = *(const float4*)(src + c * 8 + 4);
      bf16x8 o = { (bf16_t)f0.x, (bf16_t)f0.y, (bf16_t)f0.z, (bf16_t)f0.w,
                   (bf16_t)f1.x, (bf16_t)f1.y, (bf16_t)f1.z, (bf16_t)f1.w };
      *(bf16x8*)(dst + c * 8) = o;
    }
  }
  {
    const float* src = V + (size_t)(b * S_ + j0 + j) * KVD_ + kvh * D_ + d0;
    #pragma unroll
    for (int c = 0; c < 8; ++c) {
      float4 f = *(const float4*)(src + c * 4);
      tl[d0 + c * 4 + 0][j] = (bf16_t)f.x;
      tl[d0 + c * 4 + 1][j] = (bf16_t)f.y;
      tl[d0 + c * 4 + 2][j] = (bf16_t)f.z;
      tl[d0 + c * 4 + 3][j] = (bf16_t)f.w;
    }
  }
  __syncthreads();
  {
    const int d = t >> 1, half = (t & 1) * 32;
    bf16_t* dst = Vt + ((size_t)(b * KVH_ + kvh) * D_ + d) * S_ + j0 + half;
    #pragma unroll
    for (int c = 0; c < 4; ++c)
      *(bf16x8*)(dst + c * 8) = *(bf16x8*)&tl[d][half + c * 8];
  }
}

// ---------------- attention ------------------------------------------------
// wg = (b, kvh, 32-row q-tile), 512 thr = 8 waves = 4 heads x 2 row-blocks.
// KVBLK=32, LDS 40KB, double-buffered, staged via global_load_lds width=16:
// ONE instr/thread/tile/tensor, no VGPR round-trip, no cvt, no ds_writes,
// no pre-barrier vmcnt drain (the loop barrier's waitcnt covers loads issued
// a full tile of compute earlier; bf16 K/V = 2MB/XCD -> L2-resident).
// XOR swizzles live in the per-lane GLOBAL source addr; LDS dest is linear
// (a wave still covers whole rows/segments -> coalescing preserved).
// Read-side layouts identical to the r3-r7-verified kernel:
//   K : elem(row,ch,e)  at row*128 + ((ch ^ (row&15))<<3) + e
//   V^T: elem(d,chk,tk) at d*32 + ((chk ^ ((d>>1)&3) ^ ((d>>4)&3))<<3) + tk
// s_setprio REMOVED (m190: hurts barrier-lockstep structures; never A/B'd).
__global__ __launch_bounds__(512, 4) void attn_fwd(
    const float* __restrict__ Q, const bf16_t* __restrict__ Kb,
    const bf16_t* __restrict__ Vt, float* __restrict__ Out)
{
  const int fid = blockIdx.x + 32 * (blockIdx.y + 8 * (int)blockIdx.z);
  const int x   = fid & 7;                 // XCD
  const int u   = fid >> 3;                // 0..127
  const int v   = u >> 5;                  // 0..3
  const int q   = ((u & 31) + (v << 3)) & 31;   // class-mixed q-tile
  const int i0  = q * 32;
  const int hd  = x * 4 + v;               // 0..31
  const int kvh = hd & 7;
  const int b   = hd >> 3;

  const int tid  = threadIdx.x;
  const int w    = tid >> 6;
  const int lane = tid & 63;
  const int m16  = lane & 15;
  const int quad = lane >> 4;
  const int g    = w & 3;
  const int rb   = w >> 2;
  const int h    = kvh * 4 + g;
  const int iw   = i0 + rb * 16;
  const int i    = iw + m16;
  const int sw16 = (m16 >> 1) & 3;

  __shared__ __align__(16) bf16_t KsB[2][32 * 128];  // 8KB x2
  __shared__ __align__(16) bf16_t VtB[2][128 * 32];  // 8KB x2 (V^T)
  __shared__ __align__(16) bf16_t PsB[8 * 16 * 32];  // 8KB

  // Q fragments (B-operand layout)
  bf16x8 qf[4];
  {
    const float* qp = Q + ((size_t)(b * S_ + iw + m16) * H_ + h) * D_;
    #pragma unroll
    for (int s = 0; s < 4; ++s) {
      const int d0 = 32 * s + 8 * quad;
      float4 f0 = *(const float4*)(qp + d0);
      float4 f1 = *(const float4*)(qp + d0 + 4);
      bf16x8 t = { (bf16_t)f0.x, (bf16_t)f0.y, (bf16_t)f0.z, (bf16_t)f0.w,
                   (bf16_t)f1.x, (bf16_t)f1.y, (bf16_t)f1.z, (bf16_t)f1.w };
      qf[s] = t;
    }
  }

  f32x4 O[8];
  #pragma unroll
  for (int c = 0; c < 8; ++c) O[c] = (f32x4){0.f, 0.f, 0.f, 0.f};
  f32x4 lacc = (f32x4){0.f, 0.f, 0.f, 0.f};

  const bf16_t* khead = Kb + (size_t)(b * KVH_ + kvh) * S_ * D_;
  const bf16_t* vhead = Vt + (size_t)(b * KVH_ + kvh) * D_ * S_;

  // staging: chunk c = tid (512 x 16B = one 8KB tile per tensor)
  // K: row = c>>4, slot = c&15 -> source chunk = slot ^ (row&15)
  const int krow = tid >> 4;
  const int kch  = (tid & 15) ^ (krow & 15);
  const bf16_t* ksrc = khead + (size_t)krow * D_ + kch * 8;
  // V^T: d = c>>2, slot = c&3 -> source chunk = slot ^ ((d>>1)&3) ^ ((d>>4)&3)
  const int vd  = tid >> 2;
  const int vch = (tid & 3) ^ ((vd >> 1) & 3) ^ ((vd >> 4) & 3);
  const bf16_t* vsrc = vhead + (size_t)vd * S_ + vch * 8;
  bf16_t* const klds = &KsB[0][0] + w * 512;   // wave-uniform bases
  bf16_t* const vlds = &VtB[0][0] + w * 512;

  const int t_lo = (i0 >= WIN_) ? ((i0 - (WIN_ - 1)) >> 5) : 0;
  const int t_hi = i0 >> 5;

  auto stage = [&](int j0v, int bi) {
    async16(ksrc + (size_t)j0v * D_, klds + bi * (32 * 128));
    async16(vsrc + j0v,              vlds + bi * (128 * 32));
  };

  stage(t_lo * 32, 0);
  __syncthreads();           // drains prologue loads
  int buf = 0;

  for (int tb = t_lo; tb <= t_hi; ++tb) {
    const int j0  = tb * 32;
    if (tb < t_hi) stage(j0 + 32, buf ^ 1);   // in flight across the tile

    if (!(j0 > iw + 15 || j0 + 31 < iw - (WIN_ - 1))) {
      const bool full = (j0 + 31 <= iw) && (iw + 15 - j0 < WIN_);
      const int pw = w * (16 * 32);

      // ---- S^T = K·Q^T, fused softcap -> p (fixed max) -> P to LDS ----
      #pragma unroll
      for (int t4 = 0; t4 < 2; ++t4) {
        f32x4 acc = (f32x4){0.f, 0.f, 0.f, 0.f};
        const int row = 16 * t4 + m16;
        #pragma unroll
        for (int s = 0; s < 4; ++s) {
          bf16x8 a = *(const bf16x8*)&KsB[buf][row * 128 + (((quad + 4 * s) ^ m16) << 3)];
          acc = __builtin_amdgcn_mfma_f32_16x16x32_bf16(a, qf[s], acc, 0, 0, 0);
        }
        bf16x4 pk;
        #pragma unroll
        for (int r = 0; r < 4; ++r) {
          float ez = EXP2F_(acc[r] * C1_);
          float p  = EXP2F_(NK22_ * __builtin_amdgcn_rcpf(ez + 1.f));
          if (!full) {
            const int j = j0 + t4 * 16 + 4 * quad + r;
            p = ((j <= i) && (i - j < WIN_)) ? p : 0.f;
          }
          lacc[r] += p;
          pk[r] = (bf16_t)p;
        }
        const int ch = (2 * t4 + (quad >> 1)) ^ sw16;
        *(bf16x4*)&PsB[pw + m16 * 32 + ch * 8 + (quad & 1) * 4] = pk;
      }
      bf16x8 pa = *(const bf16x8*)&PsB[pw + m16 * 32 + ((quad ^ sw16) << 3)];

      // ---- O += P·V  (V^T read: chunk = quad ^ sw16 ^ (c&3)) ----
      #pragma unroll
      for (int c = 0; c < 8; ++c) {
        const int vrow = 16 * c + m16;
        bf16x8 vv = *(const bf16x8*)&VtB[buf][vrow * 32 + (((quad ^ sw16) ^ (c & 3)) << 3)];
        O[c] = __builtin_amdgcn_mfma_f32_16x16x32_bf16(pa, vv, O[c], 0, 0, 0);
      }
    }

    __syncthreads();   // publishes buf^1 (drains async loads + LDS ops)
    buf ^= 1;
  }

  // ---- epilogue: one deferred row-sum reduce, then scale + store ----
  float l_run = lacc[0] + lacc[1] + lacc[2] + lacc[3];
  l_run += __shfl_xor(l_run, 16);
  l_run += __shfl_xor(l_run, 32);

  float* ob = Out + ((size_t)(b * S_ + iw) * H_ + h) * D_;
  #pragma unroll
  for (int r = 0; r < 4; ++r) {
    const int rr = 4 * quad + r;
    const float lr = __shfl(l_run, rr);
    const float linv = __builtin_amdgcn_rcpf(lr);
    float* po = ob + (size_t)rr * (H_ * D_);
    #pragma unroll
    for (int c = 0; c < 8; ++c) po[c * 16 + m16] = O[c][r] * linv;
  }
}

extern "C" void kernel_launch(void* const* d_in, const int* in_sizes, int n_in,
                              void* d_out, int out_size, void* d_ws, size_t ws_size,
                              hipStream_t stream) {
  const float* q = (const float*)d_in[0];
  const float* k = (const float*)d_in[1];
  const float* v = (const float*)d_in[2];
  float* out = (float*)d_out;
  const size_t nkv = (size_t)B_ * KVH_ * S_ * D_;   // 4.19M elems per tensor
  bf16_t *kb, *vt;
  if (ws_size >= 2 * nkv * sizeof(bf16_t)) {
    kb = (bf16_t*)d_ws; vt = kb + nkv;
  } else {
    // k_cache/v_cache are dead inputs (identity round-trip) - reuse as scratch
    kb = (bf16_t*)d_in[3]; vt = (bf16_t*)d_in[4];
  }
  prep_kv<<<dim3(S_ / 64, KVH_, B_), 256, 0, stream>>>(k, v, kb, vt);
  attn_fwd<<<dim3(S_ / 32, KVH_, B_), 512, 0, stream>>>(q, kb, vt, out);
}